// Round 1
// 1800.553 us; speedup vs baseline: 1.3715x; 1.3715x over previous
//
#include <hip/hip_runtime.h>
#include <cstdint>
#include <cstddef>

typedef __bf16 bf16x8 __attribute__((ext_vector_type(8)));
typedef __bf16 bf16x4 __attribute__((ext_vector_type(4)));
typedef float  f32x4  __attribute__((ext_vector_type(4)));

// ---------------- ws layout (bytes) ----------------
#define WS_WFRAG   0            // 12,582,912 : fused W bf16 fragments
#define WS_XB      12582912     // 16,777,216 : x in bf16
// fallback (depth-2) layout:
#define WS_HBUF    29360128     // 131,072    : h double buffer
#define WS_CNT_FB  29491200     // 4,096      : counters
#define WS_FB_NEEDED 29495296
// fresh (depth-512) layout:
#define WS_XCHG    29360128     // 33,554,432 : 512 slots * 64 KiB
#define WS_CNT_FR  62914560     // 4,096
#define WS_FRESH_NEEDED 62918656

// LDS layout (bytes): X0 @0 (16384) | X1 @16384 (16384) | H @32768 (32768) | W @65536 (98304)
#define LDS_BYTES  163840

__device__ __forceinline__ void gload16(const void* g, void* l) {
    __builtin_amdgcn_global_load_lds(
        (const __attribute__((address_space(1))) void*)(g),
        (__attribute__((address_space(3))) void*)(l),
        16, 0, 0);
}

__device__ __forceinline__ float sigmoidf_(float x) {
    return 1.f / (1.f + __expf(-x));
}
__device__ __forceinline__ float tanhf_(float x) {
    x = fminf(fmaxf(x, -15.f), 15.f);
    float e2 = __expf(2.f * x);
    return (e2 - 1.f) / (e2 + 1.f);
}

// ---- prep: shuffle fused W = [Wx ; Wh] into bf16 B-fragment order ----
__global__ void __launch_bounds__(256) prep_w_kernel(const float* __restrict__ Wx,
                                                     const float* __restrict__ Wh,
                                                     __bf16* __restrict__ wfrag) {
    int tid = blockIdx.x * 256 + threadIdx.x;   // 0 .. 786431
    int l   = tid & 63;
    int m   = tid >> 6;
    int nt  = m & 1;
    int sk  = m >> 1;
    int kk  = sk % 48;
    int s   = sk / 48;
    int lc  = l & 15;
    int c   = nt * 16 + lc;
    int uu  = c >> 2;
    int gi  = c & 3;
    int n   = gi * 1024 + s * 8 + uu;
    int k0  = kk * 32 + (l >> 4) * 8;
    bf16x8 v;
#pragma unroll
    for (int j = 0; j < 8; ++j) {
        int k  = k0 + j;
        float f = (k < 512) ? Wx[k * 4096 + n] : Wh[(k - 512) * 4096 + n];
        v[j] = (__bf16)f;
    }
    ((bf16x8*)wfrag)[tid] = v;
}

// ---- prep: cast data fp32 -> bf16 ----
__global__ void __launch_bounds__(256) prep_x_kernel(const float* __restrict__ data,
                                                     __bf16* __restrict__ xb) {
    int tid = blockIdx.x * 256 + threadIdx.x;
    float4 v = ((const float4*)data)[tid];
    bf16x4 o;
    o[0] = (__bf16)v.x; o[1] = (__bf16)v.y; o[2] = (__bf16)v.z; o[3] = (__bf16)v.w;
    ((bf16x4*)xb)[tid] = o;
}

// ---- persistent LSTM kernel ----
// grid = 256 blocks x 128 threads. block -> (g = bid>>7, s = bid&127).
// FRESH=1: h exchange via depth-512 fresh-address bf16 buffer. Producers write
//   256 B (2 whole cache lines, single-block-owned) with device-scope stores
//   (write-through to L3); consumers read with PLAIN cached loads -> L2 acts as
//   the broadcast tree (each line written exactly once per dispatch => no stale
//   line can exist in any L1/L2 before its producer's write reaches L3, which
//   the counter barrier orders before any read).
// FRESH=0: legacy depth-2 buffer + agent-scope atomic loads (L2 bypass).
template <bool FRESH>
__global__ void __launch_bounds__(128)
lstm_main(const __bf16* __restrict__ xb, const __bf16* __restrict__ wfrag,
          const float* __restrict__ bias, float* __restrict__ out,
          __bf16* __restrict__ hbuf, unsigned* __restrict__ cnt) {
    extern __shared__ char smem[];
    __bf16* X_lds = (__bf16*)smem;                 // 2 buffers * 16 chunks * 512 bf16
    __bf16* H_lds = (__bf16*)(smem + 32768);       // 32 chunks * 512 bf16
    __bf16* W_lds = (__bf16*)(smem + 65536);       // 96 chunks * 512 bf16

    const int tid = threadIdx.x;
    const int l   = tid & 63;
    const int w   = tid >> 6;        // wave id == N-tile id (0,1)
    const int q   = l >> 4;
    const int r   = l & 15;
    const int bid = blockIdx.x;
    const int s   = bid & 127;
    const int g   = bid >> 7;
    const int gb0 = g * 16;

    // ---- stage W slice into LDS (once) ----
    const __bf16* wsrc = wfrag + (size_t)s * 49152;
    for (int m = w * 48; m < w * 48 + 48; ++m) {
        gload16(wsrc + m * 512 + l * 8, W_lds + m * 512);
    }

    const int uu = w * 4 + q;
    const int u  = s * 8 + uu;
    const float b_i = bias[u];
    const float b_f = bias[1024 + u];
    const float b_g = bias[2048 + u];
    const float b_o = bias[3072 + u];
    float cst = 0.f;

    unsigned* cbase = cnt + g * 512;             // 8 lines * 64 uints
    unsigned* mycnt = cbase + (s & 7) * 64;

    // ---- prefetch x_0 into X buffer 0 ----
    {
        const __bf16* xrow = xb + (size_t)(gb0 + r) * 512 * 512;
#pragma unroll
        for (int j = 0; j < 8; ++j) {
            int m = w * 8 + j;
            gload16(xrow + m * 32 + q * 8, X_lds + m * 512);
        }
    }

    __syncthreads();   // W + x_0 staged (drains vmcnt)

    for (int t = 0; t < 512; ++t) {
        // ---- issue h_t loads into registers ----
        unsigned long long va[16], vb[16];
        if constexpr (FRESH) {
            // plain cached loads; fresh addresses every step => never stale.
            // wave-instruction covers 1 KiB contiguous (fully coalesced).
            const __bf16* hsrc = hbuf + (size_t)t * 32768 + (size_t)g * 16384;
#pragma unroll
            for (int j = 0; j < 16; ++j) {
                int m = w * 16 + j;
                ulonglong2 v = *(const ulonglong2*)(hsrc + (m * 4 + q) * 128 + r * 8);
                va[j] = v.x; vb[j] = v.y;
            }
        } else {
            const __bf16* hsrc = hbuf + (size_t)((t & 1) * 32 + gb0) * 1024;
#pragma unroll
            for (int j = 0; j < 16; ++j) {
                int kh = (w * 16 + j) * 32 + q * 8;
                const unsigned long long* p =
                    (const unsigned long long*)(hsrc + (size_t)r * 1024 + kh);
                va[j] = __hip_atomic_load(p,     __ATOMIC_RELAXED, __HIP_MEMORY_SCOPE_AGENT);
                vb[j] = __hip_atomic_load(p + 1, __ATOMIC_RELAXED, __HIP_MEMORY_SCOPE_AGENT);
            }
        }

        // ---- x-part MFMAs overlap the h-load latency (X_lds ready since last barrier) ----
        const __bf16* Xc = X_lds + (t & 1) * 8192;
        f32x4 acc0 = {0.f, 0.f, 0.f, 0.f};
        f32x4 acc1 = {0.f, 0.f, 0.f, 0.f};
#pragma unroll
        for (int kk = 0; kk < 16; kk += 2) {
            bf16x8 a0 = *(const bf16x8*)(Xc + kk * 512 + l * 8);
            bf16x8 b0 = *(const bf16x8*)(W_lds + (kk * 2 + w) * 512 + l * 8);
            acc0 = __builtin_amdgcn_mfma_f32_16x16x32_bf16(a0, b0, acc0, 0, 0, 0);
            bf16x8 a1 = *(const bf16x8*)(Xc + (kk + 1) * 512 + l * 8);
            bf16x8 b1 = *(const bf16x8*)(W_lds + ((kk + 1) * 2 + w) * 512 + l * 8);
            acc1 = __builtin_amdgcn_mfma_f32_16x16x32_bf16(a1, b1, acc1, 0, 0, 0);
        }

        // ---- stage h into LDS (cross-wave share) ----
#pragma unroll
        for (int j = 0; j < 16; ++j) {
            int m = w * 16 + j;
            unsigned long long tmp[2] = {va[j], vb[j]};
            *((ulonglong2*)(H_lds + m * 512 + l * 8)) = *(const ulonglong2*)tmp;
        }
        __syncthreads();   // h staged; x_t prefetch drained at last release barrier

        // ---- h-part MFMAs: 32 chained, 2 accumulators ----
#pragma unroll 4
        for (int kk = 16; kk < 48; kk += 2) {
            bf16x8 a0 = *(const bf16x8*)(H_lds + (kk - 16) * 512 + l * 8);
            bf16x8 b0 = *(const bf16x8*)(W_lds + (kk * 2 + w) * 512 + l * 8);
            acc0 = __builtin_amdgcn_mfma_f32_16x16x32_bf16(a0, b0, acc0, 0, 0, 0);
            bf16x8 a1 = *(const bf16x8*)(H_lds + (kk - 15) * 512 + l * 8);
            bf16x8 b1 = *(const bf16x8*)(W_lds + ((kk + 1) * 2 + w) * 512 + l * 8);
            acc1 = __builtin_amdgcn_mfma_f32_16x16x32_bf16(a1, b1, acc1, 0, 0, 0);
        }

        // ---- regroup gates via scratch overlaid on the DEAD x buffer ----
        float*  scr   = (float*)(smem + ((t + 1) & 1) * 16384);
        __bf16* hpack = (__bf16*)(smem + ((t + 1) & 1) * 16384 + 2176);
        float* sw = scr + w * 272;
#pragma unroll
        for (int rg = 0; rg < 4; ++rg) {
            sw[(l & 15) * 17 + q * 4 + rg] = acc0[rg] + acc1[rg];
        }
        float xi = sw[(q * 4 + 0) * 17 + r];
        float xf = sw[(q * 4 + 1) * 17 + r];
        float xg = sw[(q * 4 + 2) * 17 + r];
        float xo = sw[(q * 4 + 3) * 17 + r];

        float ii = sigmoidf_(xi + b_i);
        float ff = sigmoidf_(xf + b_f);
        float gg = tanhf_(xg + b_g);
        float oo = sigmoidf_(xo + b_o);
        cst = ff * cst + ii * gg;
        float h = oo * tanhf_(cst);

        const int bglob = gb0 + r;

        if (t < 511) {
            hpack[r * 8 + uu] = (__bf16)h;
            __syncthreads();   // hpack ready (both waves done with MFMA/scratch)
            if (w == 0) {
                // wave0 stores h piece, drains at WAVE level, then signals.
                if (tid < 32) {
                    unsigned long long v = ((const unsigned long long*)hpack)[tid];
                    if constexpr (FRESH) {
                        // block-major: 256 B contiguous per (t+1, g, s) = 2 whole lines
                        unsigned long long* dst = (unsigned long long*)
                            (hbuf + (size_t)(t + 1) * 32768 + (size_t)g * 16384 + s * 128) + tid;
                        __hip_atomic_store(dst, v, __ATOMIC_RELAXED, __HIP_MEMORY_SCOPE_AGENT);
                    } else {
                        int row  = tid >> 1;
                        int half = tid & 1;
                        unsigned long long* dst = (unsigned long long*)
                            (hbuf + (size_t)(((t + 1) & 1) * 32 + gb0 + row) * 1024 + s * 8) + half;
                        __hip_atomic_store(dst, v, __ATOMIC_RELAXED, __HIP_MEMORY_SCOPE_AGENT);
                    }
                }
                __asm__ __volatile__("s_waitcnt vmcnt(0)" ::: "memory");
                if (tid == 0) {
                    __hip_atomic_fetch_add(mycnt, 1u, __ATOMIC_RELAXED, __HIP_MEMORY_SCOPE_AGENT);
                }
            }
            // ---- off-critical-path work overlapping the poll ----
            out[((size_t)bglob * 512 + t) * 1024 + u] = h;
            {   // prefetch x_{t+1} into X[(t+1)&1] (clobbers scr/hpack — both dead)
                const __bf16* xrow = xb + ((size_t)(gb0 + r) * 512 + (t + 1)) * 512;
                __bf16* Xn = X_lds + ((t + 1) & 1) * 8192;
#pragma unroll
                for (int j = 0; j < 8; ++j) {
                    int m = w * 8 + j;
                    gload16(xrow + m * 32 + q * 8, Xn + m * 512);
                }
            }
            if (tid == 0) {
                const unsigned target = 128u * (unsigned)(t + 1);
                for (;;) {
                    unsigned sum = 0;
#pragma unroll
                    for (int i = 0; i < 8; ++i)
                        sum += __hip_atomic_load(cbase + i * 64, __ATOMIC_RELAXED,
                                                 __HIP_MEMORY_SCOPE_AGENT);
                    if (sum >= target) break;
                }
            }
            __syncthreads();   // release; drains out store + x prefetch
        } else {
            out[((size_t)bglob * 512 + t) * 1024 + u] = h;
        }
    }
}

extern "C" void kernel_launch(void* const* d_in, const int* in_sizes, int n_in,
                              void* d_out, int out_size, void* d_ws, size_t ws_size,
                              hipStream_t stream) {
    const float* data = (const float*)d_in[0];
    const float* Wx   = (const float*)d_in[1];
    const float* Wh   = (const float*)d_in[2];
    const float* b    = (const float*)d_in[3];
    float* out = (float*)d_out;

    if (ws_size < (size_t)WS_FB_NEEDED) return;
    const bool fresh = ws_size >= (size_t)WS_FRESH_NEEDED;

    char* ws = (char*)d_ws;
    __bf16* wfrag = (__bf16*)(ws + WS_WFRAG);
    __bf16* xbuf  = (__bf16*)(ws + WS_XB);

    auto kFresh = lstm_main<true>;
    auto kFall  = lstm_main<false>;
    hipFuncSetAttribute((const void*)kFresh,
                        hipFuncAttributeMaxDynamicSharedMemorySize, LDS_BYTES);
    hipFuncSetAttribute((const void*)kFall,
                        hipFuncAttributeMaxDynamicSharedMemorySize, LDS_BYTES);

    prep_w_kernel<<<3072, 256, 0, stream>>>(Wx, Wh, wfrag);
    prep_x_kernel<<<8192, 256, 0, stream>>>(data, xbuf);

    if (fresh) {
        __bf16*   xchg = (__bf16*)(ws + WS_XCHG);
        unsigned* cnt  = (unsigned*)(ws + WS_CNT_FR);
        hipMemsetAsync(ws + WS_XCHG, 0, 65536, stream);    // slot 0 = h_0 = 0
        hipMemsetAsync(ws + WS_CNT_FR, 0, 4096, stream);   // counters = 0
        kFresh<<<256, 128, LDS_BYTES, stream>>>(xbuf, wfrag, b, out, xchg, cnt);
    } else {
        __bf16*   hbuf = (__bf16*)(ws + WS_HBUF);
        unsigned* cnt  = (unsigned*)(ws + WS_CNT_FB);
        hipMemsetAsync(ws + WS_HBUF, 0, 131072 + 4096, stream);
        kFall<<<256, 128, LDS_BYTES, stream>>>(xbuf, wfrag, b, out, hbuf, cnt);
    }
}